// Round 5
// baseline (334.949 us; speedup 1.0000x reference)
//
#include <hip/hip_runtime.h>
#include <math.h>

#define IMG_H 1024
#define IMG_W 1024
#define OUT_H 1025
#define OUT_W 1025
#define NIMG  16
#define TOTAL ((size_t)NIMG * OUT_H * OUT_W)

#define TILE_W 64
#define TILE_H 16
#define HALO_W 68                 // halo cols: tile_ox-2 .. tile_ox+65
#define HALO_H 18                 // halo rows: tile_oy-1 .. tile_oy+16
#define NQX    17                 // 68/4 x-quads per halo row
#define NPAIRS 9                  // 18 halo rows / 2
#define NMT    (NQX * NPAIRS)     // 153 4x2 microtiles

// Map bp (double-reflect-padded) row/col index k in [0,1026] to source image index.
__device__ __forceinline__ int refl(int k) {
    if (k >= 2) return (k <= 1025) ? (k - 2) : 1022;
    return k;
}

// Generic sobel at output (i,j) — exact f32 op order (bit-matched np in r1-r4).
__device__ __forceinline__ void sobel_generic(const float* __restrict__ img, int i, int j,
                                              float& gx, float& gy) {
    int r0 = refl(i), r1 = refl(i + 1), r2 = refl(i + 2);
    int c0 = refl(j), c1 = refl(j + 1), c2 = refl(j + 2);
    const float* p0 = img + r0 * IMG_W;
    const float* p1 = img + r1 * IMG_W;
    const float* p2 = img + r2 * IMG_W;
    float v00 = p0[c0], v01 = p0[c1], v02 = p0[c2];
    float v10 = p1[c0],               v12 = p1[c2];
    float v20 = p2[c0], v21 = p2[c1], v22 = p2[c2];

    float t = -v00;
    t = __fadd_rn(t, v02);
    t = __fadd_rn(t, -2.0f * v10);
    t = __fadd_rn(t, 2.0f * v12);
    t = __fadd_rn(t, -v20);
    gx = __fadd_rn(t, v22);

    t = -v00;
    t = __fadd_rn(t, -2.0f * v01);
    t = __fadd_rn(t, -v02);
    t = __fadd_rn(t, v20);
    t = __fadd_rn(t, 2.0f * v21);
    gy = __fadd_rn(t, v22);
}

// Sobel from preloaded 6-wide row registers (identical op order).
__device__ __forceinline__ void sobel_rows(const float R0[6], const float R1[6],
                                           const float R2[6], int p,
                                           float& gx, float& gy) {
    float v00 = R0[p], v01 = R0[p + 1], v02 = R0[p + 2];
    float v10 = R1[p],                  v12 = R1[p + 2];
    float v20 = R2[p], v21 = R2[p + 1], v22 = R2[p + 2];

    float s = -v00;
    s = __fadd_rn(s, v02);
    s = __fadd_rn(s, -2.0f * v10);
    s = __fadd_rn(s, 2.0f * v12);
    s = __fadd_rn(s, -v20);
    gx = __fadd_rn(s, v22);

    s = -v00;
    s = __fadd_rn(s, -2.0f * v01);
    s = __fadd_rn(s, -v02);
    s = __fadd_rn(s, v20);
    s = __fadd_rn(s, 2.0f * v21);
    gy = __fadd_rn(s, v22);
}

// Exact reference binning (double atan2 -> f32 chain). Bit-matched np in r1.
__device__ int classify_slow(float gx, float gy) {
    float t = (float)atan2((double)gx, (double)gy);
    float deg = __fmul_rn(t, (float)(180.0 / M_PI));
    float th = __fadd_rn(deg, 90.0f);
    th = fmodf(th, 180.0f);
    if (th < 0.0f) th += 180.0f;
    if (th < 22.5f || th >= 157.5f) return 0;
    if (th < 67.5f) return 1;
    if (th < 112.5f) return 2;
    return 3;
}

// Branchless fast binning with guard band; rare lanes defer to the exact chain.
// Semantics identical to the r2-r4 classify (bit-matched np).
__device__ __forceinline__ int classify(float gx, float gy) {
    float ax = fabsf(gx), ay = fabsf(gy);
    const float T22_LO = 0.414172141e0f;
    const float T22_HI = 0.414254984e0f;
    const float T67_LO = 2.413972141e0f;
    const float T67_HI = 2.414454984e0f;

    bool in22 = (ax > ay * T22_LO) && (ax < ay * T22_HI);
    bool in67 = (ax > ay * T67_LO) && (ax < ay * T67_HI);
    if (__builtin_expect(in22 || in67, 0))
        return classify_slow(gx, gy);

    unsigned s = (__float_as_uint(gx) ^ __float_as_uint(gy)) >> 31;
    int diag = s ? 1 : 3;
    return (ax <= ay * T22_LO) ? 2 : ((ax >= ay * T67_HI) ? 0 : diag);
}

__device__ __forceinline__ float mag(float gx, float gy) {
    return __fsqrt_rn(__fadd_rn(__fmul_rn(gx, gx), __fmul_rn(gy, gy)));
}

__device__ __forceinline__ void load6(const float* __restrict__ p, float v[6]) {
    float4 a = *(const float4*)p;        // 16B aligned by construction
    float2 b = *(const float2*)(p + 4);
    v[0] = a.x; v[1] = a.y; v[2] = a.z; v[3] = a.w; v[4] = b.x; v[5] = b.y;
}

__device__ __forceinline__ unsigned byteN(unsigned wa, unsigned wb, int k) {
    // bins for halo cols c..c+7 packed in two dwords; k constant after unroll
    return (k < 4) ? ((wa >> (8 * k)) & 0xffu) : ((wb >> (8 * (k - 4))) & 0xffu);
}

__global__ __launch_bounds__(256) void canny_kernel(const float* __restrict__ images,
                                                    float* __restrict__ out) {
    __shared__ float    g_s[HALO_H * HALO_W];
    __shared__ unsigned b_u[HALO_H * NQX];

    const int tile_ox = blockIdx.x * TILE_W;
    const int tile_oy = blockIdx.y * TILE_H;
    const int n       = blockIdx.z;
    const float* img = images + (size_t)n * IMG_H * IMG_W;
    const int t = threadIdx.x;

    // ---- Phase 1: g + bin for the 18x68 halo; one 4x2 microtile per thread ----
    if (t < NMT) {
        int my  = t / NQX;                // 0..8 (halo row pair)
        int qx  = t - my * NQX;           // 0..16
        int hy0 = my * 2;
        int oy0 = tile_oy + hy0 - 1;
        int ox0 = tile_ox + qx * 4 - 2;   // ≡ 2 (mod 4)

        float    gq[2][4];
        unsigned bq[2][4];

        if (oy0 >= 2 && oy0 <= 1022 && ox0 >= 2 && ox0 <= 1020) {
            // Interior: output rows oy0,oy0+1 need image rows oy0-2..oy0+1.
            const float* rp = img + (oy0 - 2) * IMG_W + (ox0 - 2);
            float R[4][6];
            load6(rp,               R[0]);
            load6(rp + IMG_W,       R[1]);
            load6(rp + 2 * IMG_W,   R[2]);
            load6(rp + 3 * IMG_W,   R[3]);
            #pragma unroll
            for (int rr = 0; rr < 2; rr++) {
                #pragma unroll
                for (int p = 0; p < 4; p++) {
                    float gx, gy;
                    sobel_rows(R[rr], R[rr + 1], R[rr + 2], p, gx, gy);
                    gq[rr][p] = mag(gx, gy);
                    bq[rr][p] = (unsigned)classify(gx, gy);
                }
            }
        } else {
            #pragma unroll
            for (int rr = 0; rr < 2; rr++) {
                #pragma unroll
                for (int p = 0; p < 4; p++) {
                    int oy = oy0 + rr, ox = ox0 + p;
                    float g = -1.0f;
                    unsigned b = 255u;
                    if (oy >= 0 && oy < OUT_H && ox >= 0 && ox < OUT_W) {
                        float gx, gy;
                        sobel_generic(img, oy, ox, gx, gy);
                        g = mag(gx, gy);
                        b = (unsigned)classify(gx, gy);
                    }
                    gq[rr][p] = g;
                    bq[rr][p] = b;
                }
            }
        }

        #pragma unroll
        for (int rr = 0; rr < 2; rr++) {
            *(float4*)&g_s[(hy0 + rr) * HALO_W + qx * 4] =
                make_float4(gq[rr][0], gq[rr][1], gq[rr][2], gq[rr][3]);
            b_u[(hy0 + rr) * NQX + qx] =
                bq[rr][0] | (bq[rr][1] << 8) | (bq[rr][2] << 16) | (bq[rr][3] << 24);
        }
    }
    __syncthreads();

    // ---- Phase 2: NMS + thresholds; one x-quad of 4 pixels per thread ----
    {
        int r  = t >> 4;                  // 0..15 tile row
        int qx = t & 15;                  // 0..15
        int c  = qx * 4;                  // tile col base
        int oy = tile_oy + r;

        // g for halo cols c..c+7, rows r..r+2 (center row = r+1)
        int base = r * HALO_W + c;        // multiple of 4 dwords -> 16B aligned
        float4 a0 = *(const float4*)&g_s[base];
        float4 a1 = *(const float4*)&g_s[base + 4];
        float4 b0 = *(const float4*)&g_s[base + HALO_W];
        float4 b1 = *(const float4*)&g_s[base + HALO_W + 4];
        float4 c0 = *(const float4*)&g_s[base + 2 * HALO_W];
        float4 c1 = *(const float4*)&g_s[base + 2 * HALO_W + 4];
        float G0[8] = {a0.x, a0.y, a0.z, a0.w, a1.x, a1.y, a1.z, a1.w};
        float G1[8] = {b0.x, b0.y, b0.z, b0.w, b1.x, b1.y, b1.z, b1.w};
        float G2[8] = {c0.x, c0.y, c0.z, c0.w, c1.x, c1.y, c1.z, c1.w};

        unsigned B0a = b_u[r * NQX + qx],       B0b = b_u[r * NQX + qx + 1];
        unsigned B1a = b_u[(r + 1) * NQX + qx], B1b = b_u[(r + 1) * NQX + qx + 1];
        unsigned B2a = b_u[(r + 2) * NQX + qx], B2b = b_u[(r + 2) * NQX + qx + 1];

        float vi[4], vw[4], vs[4];
        #pragma unroll
        for (int p = 0; p < 4; p++) {
            float    gc = G1[2 + p];
            unsigned bc = byteN(B1a, B1b, 2 + p);

            // +direction neighbor (and its bin), per bc:
            // bin0:(row,col+1) bin1:(row+1,col-1) bin2:(row+1,col) bin3:(row+1,col+1)
            float n1 = (bc == 0) ? G1[3 + p]
                     : (bc == 1) ? G2[1 + p]
                     : (bc == 2) ? G2[2 + p]
                     :             G2[3 + p];
            unsigned b1 = (bc == 0) ? byteN(B1a, B1b, 3 + p)
                        : (bc == 1) ? byteN(B2a, B2b, 1 + p)
                        : (bc == 2) ? byteN(B2a, B2b, 2 + p)
                        :             byteN(B2a, B2b, 3 + p);
            float n2 = (bc == 0) ? G1[1 + p]
                     : (bc == 1) ? G0[3 + p]
                     : (bc == 2) ? G0[2 + p]
                     :             G0[1 + p];
            unsigned b2 = (bc == 0) ? byteN(B1a, B1b, 1 + p)
                        : (bc == 1) ? byteN(B0a, B0b, 3 + p)
                        : (bc == 2) ? byteN(B0a, B0b, 2 + p)
                        :             byteN(B0a, B0b, 1 + p);

            float m1 = (b1 == bc) ? n1 : 0.0f;   // OOB halo has b=255, never matches
            float m2 = (b2 == bc) ? n2 : 0.0f;
            float nmax = fmaxf(m1, m2);          // m1,m2 >= 0
            float e = (gc >= nmax) ? gc : 0.0f;

            vi[p] = (e >= 50.0f) ? 255.5f : 0.0f;
            vw[p] = (e >= 50.0f && e < 100.0f) ? 255.0f : 0.0f;
            vs[p] = (e >= 100.0f) ? 255.0f : 0.0f;
        }

        if (oy < OUT_H) {
            size_t o = (size_t)(n * OUT_H + oy) * OUT_W + (tile_ox + c);
            #pragma unroll
            for (int p = 0; p < 4; p++) {
                int ox = tile_ox + c + p;
                if (ox < OUT_W) {
                    out[o + p]             = vi[p];
                    out[TOTAL + o + p]     = vw[p];
                    out[2 * TOTAL + o + p] = vs[p];
                }
            }
        }
    }
}

extern "C" void kernel_launch(void* const* d_in, const int* in_sizes, int n_in,
                              void* d_out, int out_size, void* d_ws, size_t ws_size,
                              hipStream_t stream) {
    const float* images = (const float*)d_in[0];
    float* out = (float*)d_out;
    dim3 grid((OUT_W + TILE_W - 1) / TILE_W,   // 17
              (OUT_H + TILE_H - 1) / TILE_H,   // 65
              NIMG);                            // 16
    canny_kernel<<<grid, 256, 0, stream>>>(images, out);
}

// Round 6
// 298.411 us; speedup vs baseline: 1.1224x; 1.1224x over previous
//
#include <hip/hip_runtime.h>
#include <math.h>

#define IMG_H 1024
#define IMG_W 1024
#define OUT_H 1025
#define OUT_W 1025
#define NIMG  16
#define TOTAL ((size_t)NIMG * OUT_H * OUT_W)

#define TILE_W 64
#define TILE_H 16
#define HALO_W 68                 // ox in [tile_ox-2, tile_ox+65]
#define HALO_H 18                 // oy in [tile_oy-1, tile_oy+16]
#define NQX    17                 // 68/4 x-quads per halo row
#define NQUAD  (HALO_H * NQX)     // 306
#define NTHREADS 320

// Map bp (double-reflect-padded) row/col index k in [0,1026] to source image index.
__device__ __forceinline__ int refl(int k) {
    if (k >= 2) return (k <= 1025) ? (k - 2) : 1022;
    return k;
}

// Generic sobel at output (i,j) — exact f32 op order (bit-matched np in r1-r5).
__device__ __forceinline__ void sobel_generic(const float* __restrict__ img, int i, int j,
                                              float& gx, float& gy) {
    int r0 = refl(i), r1 = refl(i + 1), r2 = refl(i + 2);
    int c0 = refl(j), c1 = refl(j + 1), c2 = refl(j + 2);
    const float* p0 = img + r0 * IMG_W;
    const float* p1 = img + r1 * IMG_W;
    const float* p2 = img + r2 * IMG_W;
    float v00 = p0[c0], v01 = p0[c1], v02 = p0[c2];
    float v10 = p1[c0],               v12 = p1[c2];
    float v20 = p2[c0], v21 = p2[c1], v22 = p2[c2];

    float t = -v00;
    t = __fadd_rn(t, v02);
    t = __fadd_rn(t, -2.0f * v10);
    t = __fadd_rn(t, 2.0f * v12);
    t = __fadd_rn(t, -v20);
    gx = __fadd_rn(t, v22);

    t = -v00;
    t = __fadd_rn(t, -2.0f * v01);
    t = __fadd_rn(t, -v02);
    t = __fadd_rn(t, v20);
    t = __fadd_rn(t, 2.0f * v21);
    gy = __fadd_rn(t, v22);
}

// Exact reference binning (double atan2 -> f32 chain). Bit-matched np in r1.
__device__ int classify_slow(float gx, float gy) {
    float t = (float)atan2((double)gx, (double)gy);
    float deg = __fmul_rn(t, (float)(180.0 / M_PI));
    float th = __fadd_rn(deg, 90.0f);
    th = fmodf(th, 180.0f);
    if (th < 0.0f) th += 180.0f;
    if (th < 22.5f || th >= 157.5f) return 0;
    if (th < 67.5f) return 1;
    if (th < 112.5f) return 2;
    return 3;
}

// Branchless fast binning with guard band; rare lanes (~6e-3 of waves) defer to
// the exact chain. Decision semantics identical to r2-r5 (bit-matched np).
__device__ __forceinline__ int classify(float gx, float gy) {
    float ax = fabsf(gx), ay = fabsf(gy);
    const float T22_LO = 0.414172141e0f;
    const float T22_HI = 0.414254984e0f;
    const float T67_LO = 2.413972141e0f;
    const float T67_HI = 2.414454984e0f;

    bool in22 = (ax > ay * T22_LO) && (ax < ay * T22_HI);
    bool in67 = (ax > ay * T67_LO) && (ax < ay * T67_HI);
    if (__builtin_expect(in22 || in67, 0))
        return classify_slow(gx, gy);

    unsigned s = (__float_as_uint(gx) ^ __float_as_uint(gy)) >> 31;
    int diag = s ? 1 : 3;
    return (ax <= ay * T22_LO) ? 2 : ((ax >= ay * T67_HI) ? 0 : diag);
}

__device__ __forceinline__ float mag(float gx, float gy) {
    return __fsqrt_rn(__fadd_rn(__fmul_rn(gx, gx), __fmul_rn(gy, gy)));
}

__device__ __forceinline__ void load6(const float* __restrict__ p, float v[6]) {
    float4 a = *(const float4*)p;        // 16B aligned: col base ≡ 0 (mod 4)
    float2 b = *(const float2*)(p + 4);
    v[0] = a.x; v[1] = a.y; v[2] = a.z; v[3] = a.w; v[4] = b.x; v[5] = b.y;
}

__global__ __launch_bounds__(NTHREADS) void canny_kernel(const float* __restrict__ images,
                                                         float* __restrict__ out) {
    __shared__ float    g_s[HALO_H * HALO_W];
    __shared__ unsigned b_u[HALO_H * NQX];

    const int tile_ox = blockIdx.x * TILE_W;
    const int tile_oy = blockIdx.y * TILE_H;
    const int n       = blockIdx.z;
    const float* img = images + (size_t)n * IMG_H * IMG_W;
    const int t = threadIdx.x;

    // ---- Phase 1: g + bin for the 18x68 halo, one x-quad per thread ----
    if (t < NQUAD) {
        int hy  = t / NQX;
        int qx  = t - hy * NQX;
        int oy  = tile_oy + hy - 1;
        int ox0 = tile_ox + qx * 4 - 2;   // ≡ 2 (mod 4)

        float    gq[4];
        unsigned bq[4];

        if (oy >= 2 && oy <= 1023 && ox0 >= 2 && ox0 <= 1020) {
            // Interior fast path: rows oy-2..oy, cols ox0-2..ox0+3, no reflection.
            const float* r0p = img + (oy - 2) * IMG_W + (ox0 - 2);
            float R0[6], R1[6], R2[6];
            load6(r0p, R0);
            load6(r0p + IMG_W, R1);
            load6(r0p + 2 * IMG_W, R2);
            #pragma unroll
            for (int p = 0; p < 4; p++) {
                float v00 = R0[p], v01 = R0[p + 1], v02 = R0[p + 2];
                float v10 = R1[p],                  v12 = R1[p + 2];
                float v20 = R2[p], v21 = R2[p + 1], v22 = R2[p + 2];

                float s = -v00;
                s = __fadd_rn(s, v02);
                s = __fadd_rn(s, -2.0f * v10);
                s = __fadd_rn(s, 2.0f * v12);
                s = __fadd_rn(s, -v20);
                float gx = __fadd_rn(s, v22);

                s = -v00;
                s = __fadd_rn(s, -2.0f * v01);
                s = __fadd_rn(s, -v02);
                s = __fadd_rn(s, v20);
                s = __fadd_rn(s, 2.0f * v21);
                float gy = __fadd_rn(s, v22);

                gq[p] = mag(gx, gy);
                bq[p] = (unsigned)classify(gx, gy);
            }
        } else {
            // Boundary quad: per-pixel generic (reflection + bounds).
            #pragma unroll
            for (int p = 0; p < 4; p++) {
                int ox = ox0 + p;
                float g = -1.0f;
                unsigned b = 255u;
                if (oy >= 0 && oy < OUT_H && ox >= 0 && ox < OUT_W) {
                    float gx, gy;
                    sobel_generic(img, oy, ox, gx, gy);
                    g = mag(gx, gy);
                    b = (unsigned)classify(gx, gy);
                }
                gq[p] = g;
                bq[p] = b;
            }
        }

        int ldoff = hy * HALO_W + qx * 4;            // dword index, multiple of 4
        *(float4*)&g_s[ldoff] = make_float4(gq[0], gq[1], gq[2], gq[3]);
        b_u[hy * NQX + qx] = bq[0] | (bq[1] << 8) | (bq[2] << 16) | (bq[3] << 24);
    }
    __syncthreads();

    // ---- Phase 2: NMS + thresholds from LDS (dense lane->pixel mapping) ----
    const unsigned char* b_s = (const unsigned char*)b_u;
    float* const out_i = out;
    float* const out_w = out + TOTAL;
    float* const out_s = out + 2 * TOTAL;
    #pragma unroll
    for (int q = 0; q < 4; q++) {
        int p = t + NTHREADS * q;
        if (p >= TILE_W * TILE_H) break;             // only q=3 is partial
        int r = p >> 6, c = p & 63;
        int oy = tile_oy + r, ox = tile_ox + c;
        if (oy >= OUT_H || ox >= OUT_W) continue;

        int hc = (r + 1) * HALO_W + (c + 2);
        float gc = g_s[hc];
        int   bc = b_s[hc];

        int doff = (bc == 0) ? 1
                 : (bc == 1) ? (HALO_W - 1)
                 : (bc == 2) ? HALO_W
                 :             (HALO_W + 1);

        float nmax = 0.0f;
        float g1 = g_s[hc + doff];
        if (b_s[hc + doff] == bc && g1 > nmax) nmax = g1;
        float g2 = g_s[hc - doff];
        if (b_s[hc - doff] == bc && g2 > nmax) nmax = g2;

        float e = (gc >= nmax) ? gc : 0.0f;

        size_t o = (size_t)(n * OUT_H + oy) * OUT_W + ox;
        __builtin_nontemporal_store((e >= 50.0f) ? 255.5f : 0.0f, out_i + o);
        __builtin_nontemporal_store((e >= 50.0f && e < 100.0f) ? 255.0f : 0.0f, out_w + o);
        __builtin_nontemporal_store((e >= 100.0f) ? 255.0f : 0.0f, out_s + o);
    }
}

extern "C" void kernel_launch(void* const* d_in, const int* in_sizes, int n_in,
                              void* d_out, int out_size, void* d_ws, size_t ws_size,
                              hipStream_t stream) {
    const float* images = (const float*)d_in[0];
    float* out = (float*)d_out;
    dim3 grid((OUT_W + TILE_W - 1) / TILE_W,   // 17
              (OUT_H + TILE_H - 1) / TILE_H,   // 65
              NIMG);                            // 16
    canny_kernel<<<grid, NTHREADS, 0, stream>>>(images, out);
}